// Round 1
// baseline (184.579 us; speedup 1.0000x reference)
//
#include <hip/hip_runtime.h>
#include <cstdint>
#include <cstddef>

typedef __attribute__((ext_vector_type(8))) __bf16 bf16x8;
typedef __attribute__((ext_vector_type(4))) __bf16 bf16x4;
typedef __attribute__((ext_vector_type(4))) float f32x4;

#define DEVI __device__ __forceinline__

DEVI void gload_lds16(const void* g, void* l) {
    __builtin_amdgcn_global_load_lds((const __attribute__((address_space(1))) void*)g,
                                     (__attribute__((address_space(3))) void*)l, 16, 0, 0);
}

// ---------------- f32 -> bf16 conversion of x and all weights ----------------
__global__ __launch_bounds__(256) void cvt_all(
    const float* __restrict__ x, const float* __restrict__ wq,
    const float* __restrict__ wk, const float* __restrict__ wv,
    const float* __restrict__ wo,
    bf16x4* __restrict__ xb, bf16x4* __restrict__ wqb, bf16x4* __restrict__ wkb,
    bf16x4* __restrict__ wvb, bf16x4* __restrict__ wob)
{
    int i = blockIdx.x * 256 + threadIdx.x;
    const int stride = gridDim.x * 256;
    for (; i < 1835008; i += stride) {
        const float4* s; bf16x4* d; int j;
        if (i < 1048576)      { s = (const float4*)x;  d = xb;  j = i; }
        else if (i < 1310720) { s = (const float4*)wq; d = wqb; j = i - 1048576; }
        else if (i < 1441792) { s = (const float4*)wk; d = wkb; j = i - 1310720; }
        else if (i < 1572864) { s = (const float4*)wv; d = wvb; j = i - 1441792; }
        else                  { s = (const float4*)wo; d = wob; j = i - 1572864; }
        float4 v = s[j];
        bf16x4 o = { (__bf16)v.x, (__bf16)v.y, (__bf16)v.z, (__bf16)v.w };
        d[j] = o;
    }
}

// ---------------- RoPE tables: sin/cos[t][pair], T=2048, 32 pairs ----------------
__global__ __launch_bounds__(256) void rope_tables(float* __restrict__ sint, float* __restrict__ cost)
{
    int i = blockIdx.x * 256 + threadIdx.x;   // 0..65535
    int t = i >> 5, p = i & 31;
    float inv = powf(10000.0f, -(float)p / 32.0f);
    float f = (float)t * inv;
    float s, c;
    sincosf(f, &s, &c);
    sint[i] = s;
    cost[i] = c;
}

// ---------------- QKV projection GEMM (128x128 tile, BK=64, bf16 MFMA) ----------------
// out[m][n] = sum_k x[m][k] * W[n][k];  epilogue: RoPE (q,k), q *= 0.125, scatter to
// Q[b][h][t][d], K[b][kvh][t][d], V[b][kvh][t][d]  (bf16)
__global__ __launch_bounds__(256) void qkv_gemm(
    const __bf16* __restrict__ xb, const __bf16* __restrict__ wqb,
    const __bf16* __restrict__ wkb, const __bf16* __restrict__ wvb,
    const float* __restrict__ sint, const float* __restrict__ cost,
    __bf16* __restrict__ Qo, __bf16* __restrict__ Ko, __bf16* __restrict__ Vo)
{
    __shared__ __bf16 As[8192];   // [128 rows][64 cols], 128B rows, chunk-swizzled
    __shared__ __bf16 Bs[8192];
    const int tid = threadIdx.x;
    const int lane = tid & 63;
    const int wid = tid >> 6;
    const int wm = (wid >> 1) * 64, wn = (wid & 1) * 64;
    const int m0 = blockIdx.y * 128;
    const int n0 = blockIdx.x * 128;

    const __bf16* bsrc;
    if (n0 < 1024)      bsrc = wqb + (size_t)n0 * 1024;
    else if (n0 < 1536) bsrc = wkb + (size_t)(n0 - 1024) * 1024;
    else                bsrc = wvb + (size_t)(n0 - 1536) * 1024;
    const __bf16* asrc = xb + (size_t)m0 * 1024;

    f32x4 acc[4][4] = {};
    const int srow = tid >> 3, schunk = tid & 7;

    for (int k0 = 0; k0 < 1024; k0 += 64) {
        __syncthreads();
#pragma unroll
        for (int it = 0; it < 4; ++it) {
            int r = srow + it * 32;
            int gc = (schunk ^ (r & 7)) * 8;      // pre-swizzled global source chunk
            gload_lds16(asrc + (size_t)r * 1024 + k0 + gc, (char*)As + r * 128 + schunk * 16);
            gload_lds16(bsrc + (size_t)r * 1024 + k0 + gc, (char*)Bs + r * 128 + schunk * 16);
        }
        __syncthreads();
#pragma unroll
        for (int ks = 0; ks < 2; ++ks) {
            bf16x8 af[4], bfv[4];
#pragma unroll
            for (int i = 0; i < 4; ++i) {
                int ra = wm + i * 16 + (lane & 15);
                af[i] = *(const bf16x8*)((const char*)As + ra * 128 + (((ks * 4 + (lane >> 4)) ^ (ra & 7)) * 16));
                int rb = wn + i * 16 + (lane & 15);
                bfv[i] = *(const bf16x8*)((const char*)Bs + rb * 128 + (((ks * 4 + (lane >> 4)) ^ (rb & 7)) * 16));
            }
#pragma unroll
            for (int mi = 0; mi < 4; ++mi)
#pragma unroll
                for (int ni = 0; ni < 4; ++ni)
                    acc[mi][ni] = __builtin_amdgcn_mfma_f32_16x16x32_bf16(af[mi], bfv[ni], acc[mi][ni], 0, 0, 0);
        }
    }

    const int rg = lane >> 4, cf = lane & 15;
#pragma unroll
    for (int mi = 0; mi < 4; ++mi) {
#pragma unroll
        for (int ni = 0; ni < 4; ++ni) {
#pragma unroll
            for (int r = 0; r < 4; ++r) {
                float v = acc[mi][ni][r];
                float pv = __shfl_xor(v, 1, 64);    // partner column d^1 (same rows)
                int m = m0 + wm + mi * 16 + rg * 4 + r;
                int n = n0 + wn + ni * 16 + cf;
                int b = m >> 11;
                int t = m & 2047;
                if (n < 1024) {
                    int h = n >> 6, d = n & 63;
                    float s = sint[t * 32 + (d >> 1)], c = cost[t * 32 + (d >> 1)];
                    float o = (d & 1) ? (pv * s + v * c) : (v * c - pv * s);
                    Qo[((size_t)(b * 16 + h) * 2048 + t) * 64 + d] = (__bf16)(o * 0.125f);
                } else if (n < 1536) {
                    int nn = n - 1024;
                    int h = nn >> 6, d = nn & 63;
                    float s = sint[t * 32 + (d >> 1)], c = cost[t * 32 + (d >> 1)];
                    float o = (d & 1) ? (pv * s + v * c) : (v * c - pv * s);
                    Ko[((size_t)(b * 8 + h) * 2048 + t) * 64 + d] = (__bf16)o;
                } else {
                    int nn = n - 1536;
                    int h = nn >> 6, d = nn & 63;
                    Vo[((size_t)(b * 8 + h) * 2048 + t) * 64 + d] = (__bf16)v;
                }
            }
        }
    }
}

// ---------------- V transpose: V[bh][t][d] -> VT[bh][d][t] ----------------
__global__ __launch_bounds__(256) void v_transpose(const __bf16* __restrict__ Vg, __bf16* __restrict__ VTg)
{
    __shared__ __bf16 tile[64][72];
    const int tid = threadIdx.x;
    const int t0 = blockIdx.x * 64;
    const int bh = blockIdx.y;
    const size_t base = (size_t)bh * 2048 * 64;
    const int rr = tid >> 3, c8 = (tid & 7) * 8;
#pragma unroll
    for (int it = 0; it < 2; ++it) {
        int tt = rr + it * 32;
        *(bf16x8*)(&tile[tt][c8]) = *(const bf16x8*)(Vg + base + (size_t)(t0 + tt) * 64 + c8);
    }
    __syncthreads();
#pragma unroll
    for (int it = 0; it < 2; ++it) {
        int d = rr + it * 32;
        bf16x8 o;
#pragma unroll
        for (int j = 0; j < 8; ++j) o[j] = tile[c8 + j][d];
        *(bf16x8*)(VTg + base + (size_t)d * 2048 + t0 + c8) = o;
    }
}

// ---------------- Flash attention (causal, GQA), Q-tile 128, KV-tile 64 ----------------
__global__ __launch_bounds__(256) void attn_fwd(
    const __bf16* __restrict__ Qg, const __bf16* __restrict__ Kg,
    const __bf16* __restrict__ VTg, __bf16* __restrict__ Yg)
{
    __shared__ __bf16 Kt[4096];   // [64 n][64 d], swizzled
    __shared__ __bf16 Vt[4096];   // [64 d][64 n], swizzled (from transposed V)
    __shared__ __bf16 Pl[8192];   // [128 rows][64 n], per-wave 32-row slices, swizzled
    const int tid = threadIdx.x;
    const int lane = tid & 63;
    const int wid = tid >> 6;
    const int qt = gridDim.x - 1 - blockIdx.x;   // big tiles first (load balance)
    const int bh = blockIdx.y;
    const int b = bh >> 4, h = bh & 15, kvh = h >> 1;
    const int q0 = qt * 128;
    const size_t qbase = (size_t)(b * 16 + h) * 2048 * 64;
    const size_t kbase = (size_t)(b * 8 + kvh) * 2048 * 64;
    const int rg = lane >> 4, cf = lane & 15;

    // Q fragments in registers (already scaled by 0.125)
    bf16x8 qf[2][2];
#pragma unroll
    for (int mi = 0; mi < 2; ++mi)
#pragma unroll
        for (int ks = 0; ks < 2; ++ks) {
            int t = q0 + wid * 32 + mi * 16 + cf;
            qf[mi][ks] = *(const bf16x8*)(Qg + qbase + (size_t)t * 64 + ks * 32 + rg * 8);
        }

    f32x4 oacc[2][4] = {};
    float mst[2][4], lst[2][4];
#pragma unroll
    for (int i = 0; i < 2; ++i)
#pragma unroll
        for (int r = 0; r < 4; ++r) { mst[i][r] = -3.0e38f; lst[i][r] = 0.0f; }

    const int ntiles = qt * 2 + 2;
    const int srow = tid >> 3, schunk = tid & 7;
    char* pw = (char*)Pl + wid * 32 * 128;

    for (int nt = 0; nt < ntiles; ++nt) {
        const int n0 = nt * 64;
        __syncthreads();
#pragma unroll
        for (int it = 0; it < 2; ++it) {
            int r = srow + it * 32;
            int gc = (schunk ^ (r & 7)) * 8;
            gload_lds16(Kg + kbase + (size_t)(n0 + r) * 64 + gc, (char*)Kt + r * 128 + schunk * 16);
            gload_lds16(VTg + kbase + (size_t)r * 2048 + n0 + gc, (char*)Vt + r * 128 + schunk * 16);
        }
        __syncthreads();

        if (n0 <= q0 + wid * 32 + 31) {   // wave-uniform skip of fully-masked tiles
            // S = Q K^T
            f32x4 sacc[2][4] = {};
#pragma unroll
            for (int ks = 0; ks < 2; ++ks) {
                bf16x8 kf[4];
#pragma unroll
                for (int ni = 0; ni < 4; ++ni) {
                    int rk = ni * 16 + cf;
                    kf[ni] = *(const bf16x8*)((const char*)Kt + rk * 128 + (((ks * 4 + rg) ^ (rk & 7)) * 16));
                }
#pragma unroll
                for (int mi = 0; mi < 2; ++mi)
#pragma unroll
                    for (int ni = 0; ni < 4; ++ni)
                        sacc[mi][ni] = __builtin_amdgcn_mfma_f32_16x16x32_bf16(qf[mi][ks], kf[ni], sacc[mi][ni], 0, 0, 0);
            }
            // online softmax
#pragma unroll
            for (int mi = 0; mi < 2; ++mi) {
#pragma unroll
                for (int r = 0; r < 4; ++r) {
                    int mrow = q0 + wid * 32 + mi * 16 + rg * 4 + r;
                    float rmax = -3.0e38f;
#pragma unroll
                    for (int ni = 0; ni < 4; ++ni) {
                        int nc = n0 + ni * 16 + cf;
                        float sv = sacc[mi][ni][r];
                        sv = (nc > mrow) ? -3.0e38f : sv;
                        sacc[mi][ni][r] = sv;
                        rmax = fmaxf(rmax, sv);
                    }
#pragma unroll
                    for (int off = 1; off < 16; off <<= 1)
                        rmax = fmaxf(rmax, __shfl_xor(rmax, off, 64));
                    float mold = mst[mi][r];
                    float mnew = fmaxf(mold, rmax);
                    float sf = __expf(mold - mnew);
                    float rs = 0.0f;
#pragma unroll
                    for (int ni = 0; ni < 4; ++ni) {
                        float p = __expf(sacc[mi][ni][r] - mnew);
                        sacc[mi][ni][r] = p;
                        rs += p;
                    }
#pragma unroll
                    for (int off = 1; off < 16; off <<= 1)
                        rs += __shfl_xor(rs, off, 64);
                    mst[mi][r] = mnew;
                    lst[mi][r] = lst[mi][r] * sf + rs;
#pragma unroll
                    for (int df = 0; df < 4; ++df) oacc[mi][df][r] *= sf;
                }
            }
            // P -> LDS (bf16, swizzled, wave-local)
#pragma unroll
            for (int mi = 0; mi < 2; ++mi)
#pragma unroll
                for (int ni = 0; ni < 4; ++ni)
#pragma unroll
                    for (int r = 0; r < 4; ++r) {
                        int pr = mi * 16 + rg * 4 + r;
                        int pc = ni * 16 + cf;
                        *(__bf16*)(pw + pr * 128 + (((pc >> 3) ^ (pr & 7)) * 8 + (pc & 7)) * 2) =
                            (__bf16)sacc[mi][ni][r];
                    }
            // O += P V
#pragma unroll
            for (int ks = 0; ks < 2; ++ks) {
                bf16x8 pf[2], vf[4];
#pragma unroll
                for (int mi = 0; mi < 2; ++mi) {
                    int pr = mi * 16 + cf;
                    pf[mi] = *(const bf16x8*)(pw + pr * 128 + (((ks * 4 + rg) ^ (pr & 7)) * 16));
                }
#pragma unroll
                for (int df = 0; df < 4; ++df) {
                    int vd = df * 16 + cf;
                    vf[df] = *(const bf16x8*)((const char*)Vt + vd * 128 + (((ks * 4 + rg) ^ (vd & 7)) * 16));
                }
#pragma unroll
                for (int mi = 0; mi < 2; ++mi)
#pragma unroll
                    for (int df = 0; df < 4; ++df)
                        oacc[mi][df] = __builtin_amdgcn_mfma_f32_16x16x32_bf16(pf[mi], vf[df], oacc[mi][df], 0, 0, 0);
            }
        }
    }

    // epilogue: Y[b][t][h*64+d] = O / l   (bf16)
#pragma unroll
    for (int mi = 0; mi < 2; ++mi)
#pragma unroll
        for (int r = 0; r < 4; ++r) {
            float inv = 1.0f / lst[mi][r];
            int t = q0 + wid * 32 + mi * 16 + rg * 4 + r;
#pragma unroll
            for (int df = 0; df < 4; ++df)
                Yg[((size_t)b * 2048 + t) * 1024 + h * 64 + df * 16 + cf] =
                    (__bf16)(oacc[mi][df][r] * inv);
        }
}

// ---------------- Output projection GEMM: out = Y @ Wo^T (f32 out) ----------------
__global__ __launch_bounds__(256) void out_gemm(
    const __bf16* __restrict__ Yb, const __bf16* __restrict__ Wob, float* __restrict__ outp)
{
    __shared__ __bf16 As[8192];
    __shared__ __bf16 Bs[8192];
    const int tid = threadIdx.x;
    const int lane = tid & 63;
    const int wid = tid >> 6;
    const int wm = (wid >> 1) * 64, wn = (wid & 1) * 64;
    const int m0 = blockIdx.y * 128;
    const int n0 = blockIdx.x * 128;
    const __bf16* asrc = Yb + (size_t)m0 * 1024;
    const __bf16* bsrc = Wob + (size_t)n0 * 1024;

    f32x4 acc[4][4] = {};
    const int srow = tid >> 3, schunk = tid & 7;

    for (int k0 = 0; k0 < 1024; k0 += 64) {
        __syncthreads();
#pragma unroll
        for (int it = 0; it < 4; ++it) {
            int r = srow + it * 32;
            int gc = (schunk ^ (r & 7)) * 8;
            gload_lds16(asrc + (size_t)r * 1024 + k0 + gc, (char*)As + r * 128 + schunk * 16);
            gload_lds16(bsrc + (size_t)r * 1024 + k0 + gc, (char*)Bs + r * 128 + schunk * 16);
        }
        __syncthreads();
#pragma unroll
        for (int ks = 0; ks < 2; ++ks) {
            bf16x8 af[4], bfv[4];
#pragma unroll
            for (int i = 0; i < 4; ++i) {
                int ra = wm + i * 16 + (lane & 15);
                af[i] = *(const bf16x8*)((const char*)As + ra * 128 + (((ks * 4 + (lane >> 4)) ^ (ra & 7)) * 16));
                int rb = wn + i * 16 + (lane & 15);
                bfv[i] = *(const bf16x8*)((const char*)Bs + rb * 128 + (((ks * 4 + (lane >> 4)) ^ (rb & 7)) * 16));
            }
#pragma unroll
            for (int mi = 0; mi < 4; ++mi)
#pragma unroll
                for (int ni = 0; ni < 4; ++ni)
                    acc[mi][ni] = __builtin_amdgcn_mfma_f32_16x16x32_bf16(af[mi], bfv[ni], acc[mi][ni], 0, 0, 0);
        }
    }

    const int rg = lane >> 4, cf = lane & 15;
#pragma unroll
    for (int mi = 0; mi < 4; ++mi)
#pragma unroll
        for (int ni = 0; ni < 4; ++ni)
#pragma unroll
            for (int r = 0; r < 4; ++r) {
                int m = m0 + wm + mi * 16 + rg * 4 + r;
                int n = n0 + wn + ni * 16 + cf;
                outp[(size_t)m * 1024 + n] = acc[mi][ni][r];
            }
}

// ---------------- launch ----------------
extern "C" void kernel_launch(void* const* d_in, const int* in_sizes, int n_in,
                              void* d_out, int out_size, void* d_ws, size_t ws_size,
                              hipStream_t stream)
{
    const float* x  = (const float*)d_in[0];
    const float* wq = (const float*)d_in[1];
    const float* wk = (const float*)d_in[2];
    const float* wv = (const float*)d_in[3];
    const float* wo = (const float*)d_in[4];

    char* ws = (char*)d_ws;
    __bf16* xb  = (__bf16*)(ws + 0);          // 8,388,608 B
    __bf16* wqb = (__bf16*)(ws + 8388608);    // 2,097,152
    __bf16* wkb = (__bf16*)(ws + 10485760);   // 1,048,576
    __bf16* wvb = (__bf16*)(ws + 11534336);   // 1,048,576
    __bf16* wob = (__bf16*)(ws + 12582912);   // 2,097,152
    __bf16* Qb  = (__bf16*)(ws + 14680064);   // 8,388,608
    __bf16* Kb  = (__bf16*)(ws + 23068672);   // 4,194,304
    __bf16* Vb  = (__bf16*)(ws + 27262976);   // 4,194,304
    __bf16* VTb = (__bf16*)(ws + 31457280);   // 4,194,304
    __bf16* Yb  = (__bf16*)(ws + 35651584);   // 8,388,608
    float* sint = (float*)(ws + 44040192);    // 262,144
    float* cost = (float*)(ws + 44302336);    // 262,144
    if (ws_size < 44564480) return;           // would fail loudly via absmax

    cvt_all<<<2048, 256, 0, stream>>>(x, wq, wk, wv, wo,
                                      (bf16x4*)xb, (bf16x4*)wqb, (bf16x4*)wkb,
                                      (bf16x4*)wvb, (bf16x4*)wob);
    rope_tables<<<256, 256, 0, stream>>>(sint, cost);
    qkv_gemm<<<dim3(16, 32), 256, 0, stream>>>(xb, wqb, wkb, wvb, sint, cost, Qb, Kb, Vb);
    v_transpose<<<dim3(32, 16), 256, 0, stream>>>(Vb, VTb);
    attn_fwd<<<dim3(16, 32), 256, 0, stream>>>(Qb, Kb, VTb, Yb);
    out_gemm<<<dim3(8, 32), 256, 0, stream>>>(Yb, wob, (float*)d_out);
}